// Round 10
// baseline (2154.566 us; speedup 1.0000x reference)
//
#include <hip/hip_runtime.h>
#include <stdint.h>

// Problem constants
#define NB 8
#define NPT 8192
#define ND 64
#define NO 128
#define NS 2048
#define NK 16
#define NCONS 248   // consumer blocks
#define NITER 67    // ceil(B*S / NCONS) = ceil(16384/248)

typedef float f32x2 __attribute__((ext_vector_type(2)));

// Workspace layout (in floats)
constexpr int WS_PTS_T  = 0;                         // [B][N][64] transposed points
constexpr int WS_XYZW   = WS_PTS_T + NB*NPT*ND;      // [B][N][4] x,y,z,|p|^2
constexpr int WS_GFAR   = WS_XYZW + NB*NPT*4;        // int [B][S] center indices, -1 = not ready
constexpr int WS_SYNC   = WS_GFAR + NB*NS;           // int[32]: prep_done at 0

// Output layout (floats): new_xyz [B][3][S], out [B][O][S], fps_idx [B][S]
constexpr int OUT_NEWXYZ = 0;
constexpr int OUT_FEAT   = NB*3*NS;
constexpr int OUT_FPS    = OUT_FEAT + NB*NO*NS;

__device__ __forceinline__ float sq3(float x, float y, float z) {
#pragma clang fp contract(off)
  return (x*x + y*y) + z*z;
}

// packed squared distance for 2 points: bit-identical op order ((dx*dx+dy*dy)+dz*dz)
__device__ __forceinline__ f32x2 fps_d2(f32x2 px, f32x2 py, f32x2 pz, f32x2 cx, f32x2 cy, f32x2 cz) {
#pragma clang fp contract(off)
  f32x2 dx = px - cx, dy = py - cy, dz = pz - cz;
  return (dx*dx + dy*dy) + dz*dz;
}

__device__ __forceinline__ float knn_d(float qn, float pn,
                                       float qx,float qy,float qz,
                                       float px,float py,float pz) {
#pragma clang fp contract(off)
  float dot = (qx*px + qy*py) + qz*pz;
  return (qn + pn) - 2.0f*dot;
}

#define DPP_STEP_F(x, ctrl, rm, bm, op) { \
  int _v = __builtin_amdgcn_update_dpp(__float_as_int(x), __float_as_int(x), ctrl, rm, bm, false); \
  x = op(x, __int_as_float(_v)); }

__device__ __forceinline__ float wave_max_dpp(float x) {
  DPP_STEP_F(x, 0x111, 0xF, 0xF, fmaxf)  // row_shr:1
  DPP_STEP_F(x, 0x112, 0xF, 0xF, fmaxf)  // row_shr:2
  DPP_STEP_F(x, 0x114, 0xF, 0xF, fmaxf)  // row_shr:4
  DPP_STEP_F(x, 0x118, 0xF, 0xF, fmaxf)  // row_shr:8
  DPP_STEP_F(x, 0x142, 0xA, 0xF, fmaxf)  // row_bcast:15
  DPP_STEP_F(x, 0x143, 0xC, 0xF, fmaxf)  // row_bcast:31
  return x;                              // valid in lane 63
}
__device__ __forceinline__ float wave_min_dpp(float x) {
  DPP_STEP_F(x, 0x111, 0xF, 0xF, fminf)
  DPP_STEP_F(x, 0x112, 0xF, 0xF, fminf)
  DPP_STEP_F(x, 0x114, 0xF, 0xF, fminf)
  DPP_STEP_F(x, 0x118, 0xF, 0xF, fminf)
  DPP_STEP_F(x, 0x142, 0xA, 0xF, fminf)
  DPP_STEP_F(x, 0x143, 0xC, 0xF, fminf)
  return x;
}
__device__ __forceinline__ unsigned wave_umax_dpp(unsigned x) {
#define DPP_STEP_U(ctrl, rm) { \
  unsigned _v = (unsigned)__builtin_amdgcn_update_dpp((int)x, (int)x, ctrl, rm, 0xF, false); \
  x = (x > _v) ? x : _v; }
  DPP_STEP_U(0x111, 0xF) DPP_STEP_U(0x112, 0xF) DPP_STEP_U(0x114, 0xF)
  DPP_STEP_U(0x118, 0xF) DPP_STEP_U(0x142, 0xA) DPP_STEP_U(0x143, 0xC)
  return x;
}
__device__ __forceinline__ float dpp8_max(float x) {
  DPP_STEP_F(x, 0x111, 0xF, 0xF, fmaxf)
  DPP_STEP_F(x, 0x112, 0xF, 0xF, fmaxf)
  DPP_STEP_F(x, 0x114, 0xF, 0xF, fmaxf)
  return x;                              // lane 7 = max of lanes 0..7
}
__device__ __forceinline__ unsigned dpp8_umax(unsigned x) {
  DPP_STEP_U(0x111, 0xF) DPP_STEP_U(0x112, 0xF) DPP_STEP_U(0x114, 0xF)
  return x;
}

__device__ __forceinline__ unsigned morton3(unsigned x, unsigned y, unsigned z) {
  unsigned m = (x & 1) | ((y & 1) << 1) | ((z & 1) << 2);
  m |= ((x & 2) << 2) | ((y & 2) << 3) | ((z & 2) << 4);
  m |= ((x & 4) << 4) | ((y & 4) << 5) | ((z & 4) << 6);
  return m;   // 9 bits, 512 cells
}

__global__ void k_init(float* __restrict__ ws) {
  int idx = blockIdx.x*512 + threadIdx.x;
  if (idx < NB*NS) ((int*)(ws + WS_GFAR))[idx] = -1;
  if (idx < 32)    ((int*)(ws + WS_SYNC))[idx] = 0;
}

struct MegaShared {
  union {
    struct {                                  // FPS producer (~138 KB)
      float lxyzo[NPT][4];                    // sorted: x,y,z,origidx-bits (128 KB)
      int hist[512];
      int tmp[512];
      int cs[512];
      float bb[8][6];
      unsigned long long wred[2][8];
      int farbuf[64];
    } f;
    struct { float tile[64][65]; } tr;        // prep transpose
    struct {                                  // consumer (~70 KB)
      float W[128*69];
      union {
        float dist[NPT];
        struct { float np[16*69]; float ft[16*132]; float chred[256]; float ptred[16*17]; } p2;
      } u;
      unsigned long long kred[8];
      int selIdx[16];
      float agg[144];
      float a2[144];
      float gates[144];
      int farSlot;
    } c;
  } u;
};

__global__ __launch_bounds__(512) void k_mega(const float* __restrict__ xyz,
                                              const float* __restrict__ points,
                                              const float* __restrict__ Wkern,
                                              const float* __restrict__ Wlin,
                                              const float* __restrict__ Wpt,
                                              const float* __restrict__ Wch,
                                              float* __restrict__ ws,
                                              float* __restrict__ dout) {
  __shared__ MegaShared sh;
  const int bid = blockIdx.x, t = threadIdx.x;
  int* syncp = (int*)(ws + WS_SYNC);
  int* gfar  = (int*)(ws + WS_GFAR);

  if (bid < NB) {
    // ================= FPS producer: Morton counting-sort + lazy bucket-skip =============
    const float* xb = xyz + (size_t)bid*3*NPT;
    const int base = t << 4;
    const int w = t >> 6;

    float lx[16], ly[16], lz[16];
#pragma unroll
    for (int jj = 0; jj < 4; jj++) {
      float4 vx = *reinterpret_cast<const float4*>(xb + base + jj*4);
      float4 vy = *reinterpret_cast<const float4*>(xb + NPT + base + jj*4);
      float4 vz = *reinterpret_cast<const float4*>(xb + 2*NPT + base + jj*4);
      lx[jj*4+0]=vx.x; lx[jj*4+1]=vx.y; lx[jj*4+2]=vx.z; lx[jj*4+3]=vx.w;
      ly[jj*4+0]=vy.x; ly[jj*4+1]=vy.y; ly[jj*4+2]=vy.z; ly[jj*4+3]=vy.w;
      lz[jj*4+0]=vz.x; lz[jj*4+1]=vz.y; lz[jj*4+2]=vz.z; lz[jj*4+3]=vz.w;
    }
    // batch bbox
    float mnx=lx[0],mxx=lx[0],mny=ly[0],mxy=ly[0],mnz=lz[0],mxz=lz[0];
#pragma unroll
    for (int j = 1; j < 16; j++) {
      mnx=fminf(mnx,lx[j]); mxx=fmaxf(mxx,lx[j]);
      mny=fminf(mny,ly[j]); mxy=fmaxf(mxy,ly[j]);
      mnz=fminf(mnz,lz[j]); mxz=fmaxf(mxz,lz[j]);
    }
    float rmnx=wave_min_dpp(mnx), rmxx=wave_max_dpp(mxx);
    float rmny=wave_min_dpp(mny), rmxy=wave_max_dpp(mxy);
    float rmnz=wave_min_dpp(mnz), rmxz=wave_max_dpp(mxz);
    if ((t & 63) == 63) {
      sh.u.f.bb[w][0]=rmnx; sh.u.f.bb[w][1]=rmxx;
      sh.u.f.bb[w][2]=rmny; sh.u.f.bb[w][3]=rmxy;
      sh.u.f.bb[w][4]=rmnz; sh.u.f.bb[w][5]=rmxz;
    }
    sh.u.f.hist[t & 511] = 0;
    __syncthreads();
    float Bmnx=sh.u.f.bb[0][0], Bmxx=sh.u.f.bb[0][1];
    float Bmny=sh.u.f.bb[0][2], Bmxy=sh.u.f.bb[0][3];
    float Bmnz=sh.u.f.bb[0][4], Bmxz=sh.u.f.bb[0][5];
#pragma unroll
    for (int ww = 1; ww < 8; ww++) {
      Bmnx=fminf(Bmnx,sh.u.f.bb[ww][0]); Bmxx=fmaxf(Bmxx,sh.u.f.bb[ww][1]);
      Bmny=fminf(Bmny,sh.u.f.bb[ww][2]); Bmxy=fmaxf(Bmxy,sh.u.f.bb[ww][3]);
      Bmnz=fminf(Bmnz,sh.u.f.bb[ww][4]); Bmxz=fmaxf(Bmxz,sh.u.f.bb[ww][5]);
    }
    float wx=Bmxx-Bmnx, wy=Bmxy-Bmny, wz=Bmxz-Bmnz;
    float invx = (wx>0.f)?(8.0f/wx):0.f;
    float invy = (wy>0.f)?(8.0f/wy):0.f;
    float invz = (wz>0.f)?(8.0f/wz):0.f;
    int cid[16];
#pragma unroll
    for (int j = 0; j < 16; j++) {
      int cxi = min(7, (int)((lx[j]-Bmnx)*invx));
      int cyi = min(7, (int)((ly[j]-Bmny)*invy));
      int czi = min(7, (int)((lz[j]-Bmnz)*invz));
      cid[j] = (int)morton3((unsigned)cxi,(unsigned)cyi,(unsigned)czi);
      atomicAdd(&sh.u.f.hist[cid[j]], 1);
    }
    __syncthreads();
    // Hillis-Steele inclusive scan over 512 bins (512 threads, ping-pong)
    {
      int* A = sh.u.f.hist; int* B = sh.u.f.tmp;
      for (int d = 1; d < 512; d <<= 1) {
        int v = A[t] + ((t >= d) ? A[t-d] : 0);
        B[t] = v;
        __syncthreads();
        int* sw = A; A = B; B = sw;
      }
      sh.u.f.cs[t] = (t == 0) ? 0 : A[t-1];
    }
    __syncthreads();
    // scatter into sorted order (origidx in .w)
#pragma unroll
    for (int j = 0; j < 16; j++) {
      int pos = atomicAdd(&sh.u.f.cs[cid[j]], 1);
      float4 rec; rec.x=lx[j]; rec.y=ly[j]; rec.z=lz[j]; rec.w=__int_as_float(base+j);
      *reinterpret_cast<float4*>(&sh.u.f.lxyzo[pos][0]) = rec;
    }
    __syncthreads();
    // reload own 16 sorted points + bucket bbox + caches
    f32x2 px2[8], py2[8], pz2[8], dist2[8];
    unsigned oi[16];
    float bmnx= 3e38f,bmxx=-3e38f,bmny= 3e38f,bmxy=-3e38f,bmnz= 3e38f,bmxz=-3e38f;
#pragma unroll
    for (int j = 0; j < 16; j++) {
      float4 r = *reinterpret_cast<const float4*>(&sh.u.f.lxyzo[base + j][0]);
      if (j & 1) { px2[j>>1].y=r.x; py2[j>>1].y=r.y; pz2[j>>1].y=r.z; }
      else       { px2[j>>1].x=r.x; py2[j>>1].x=r.y; pz2[j>>1].x=r.z; }
      oi[j] = (unsigned)__float_as_int(r.w);
      bmnx=fminf(bmnx,r.x); bmxx=fmaxf(bmxx,r.x);
      bmny=fminf(bmny,r.y); bmxy=fmaxf(bmxy,r.y);
      bmnz=fminf(bmnz,r.z); bmxz=fmaxf(bmxz,r.z);
    }
#pragma unroll
    for (int j = 0; j < 8; j++) dist2[j] = f32x2{1e10f, 1e10f};
    float cachedMax = 3e38f; unsigned cachedCand = 0;

    int far = 0;
    int* gfb = gfar + (size_t)bid*NS;

    for (int s = 0; s < NS; s++) {
      if (t == 480) sh.u.f.farbuf[s & 63] = far;
      if ((s & 31) == 0 && s > 0 && w == 1) {
        int l = t & 63;
        if (l < 32) {
          int q = s - 32 + l;
          __hip_atomic_store(&gfb[q], sh.u.f.farbuf[q & 63], __ATOMIC_RELAXED, __HIP_MEMORY_SCOPE_AGENT);
        }
      }
      // center coords: uniform (scalar) loads from original-layout xyz
      const int fr = far;
      const float cx = xb[fr], cy = xb[NPT + fr], cz = xb[2*NPT + fr];

      // bucket lower-bound test (conservative margin -> skip is provably exact)
      float ddx = fmaxf(fmaxf(bmnx - cx, cx - bmxx), 0.f);
      float ddy = fmaxf(fmaxf(bmny - cy, cy - bmxy), 0.f);
      float ddz = fmaxf(fmaxf(bmnz - cz, cz - bmxz), 0.f);
      float lb2 = ddx*ddx + ddy*ddy + ddz*ddz;

      float bv; unsigned cand;
      if (lb2 <= cachedMax * 1.0002f) {
        const f32x2 c2x = {cx, cx}, c2y = {cy, cy}, c2z = {cz, cz};
        f32x2 vmax2 = {-1.0f, -1.0f};
#pragma unroll
        for (int j = 0; j < 8; j++) {
          f32x2 dd = fps_d2(px2[j], py2[j], pz2[j], c2x, c2y, c2z);
          f32x2 nd;
          nd.x = fminf(dist2[j].x, dd.x);
          nd.y = fminf(dist2[j].y, dd.y);
          dist2[j] = nd;
          vmax2.x = fmaxf(vmax2.x, nd.x);
          vmax2.y = fmaxf(vmax2.y, nd.y);
        }
        bv = fmaxf(vmax2.x, vmax2.y);
        cand = 0;
#pragma unroll
        for (int j = 0; j < 8; j++) {
          unsigned sx = (dist2[j].x == bv) ? (8191u - oi[2*j])   : 0u;
          unsigned sy = (dist2[j].y == bv) ? (8191u - oi[2*j+1]) : 0u;
          unsigned m = (sx > sy) ? sx : sy;
          cand = (cand > m) ? cand : m;
        }
        cachedMax = bv; cachedCand = cand;
      } else {
        bv = cachedMax; cand = cachedCand;
      }
      // exact two-phase wave reduce: f32 max, then u32 max of (8191-origidx) among matches
      float wmv = wave_max_dpp(bv);
      float wmax = __int_as_float(__builtin_amdgcn_readlane(__float_as_int(wmv), 63));
      unsigned cnd = (bv == wmax) ? cand : 0u;
      unsigned wcv = wave_umax_dpp(cnd);
      unsigned wcand = (unsigned)__builtin_amdgcn_readlane((int)wcv, 63);
      const int par = s & 1;
      if ((t & 63) == 0)
        sh.u.f.wred[par][w] = ((unsigned long long)__float_as_uint(wmax) << 32) | wcand;
      __syncthreads();
      // stage 2: same two-phase over the 8 wave slots
      unsigned long long kk = sh.u.f.wred[par][t & 7];
      float sv = __int_as_float((int)(unsigned)(kk >> 32));
      float sm = dpp8_max(sv);
      float M = __int_as_float(__builtin_amdgcn_readlane(__float_as_int(sm), 7));
      unsigned c2v = (sv == M) ? (unsigned)(kk & 0xFFFFFFFFull) : 0u;
      unsigned s2v = dpp8_umax(c2v);
      unsigned W = (unsigned)__builtin_amdgcn_readlane((int)s2v, 7);
      far = __builtin_amdgcn_readfirstlane(8191 - (int)W);
    }
    // tail flush: centers NS-32 .. NS-1
    if (w == 1) {
      int l = t & 63;
      if (l < 32) {
        int q = NS - 32 + l;
        __hip_atomic_store(&gfb[q], sh.u.f.farbuf[q & 63], __ATOMIC_RELAXED, __HIP_MEMORY_SCOPE_AGENT);
      }
    }
    return;
  }

  // ================= Consumer block (unchanged from R9) =================
  const int cbid = bid - NB;   // 0..247

  for (int tile = cbid; tile < 1024; tile += NCONS) {
    const int b  = tile >> 7;
    const int n0 = (tile & 127) << 6;
    const float* pb = points + (size_t)b*ND*NPT;
    {
      int dR = t >> 3, cg = t & 7;
      const float* src = pb + (size_t)dR*NPT + n0 + cg*8;
      float4 v0 = *reinterpret_cast<const float4*>(src);
      float4 v1 = *reinterpret_cast<const float4*>(src + 4);
      sh.u.tr.tile[dR][cg*8+0]=v0.x; sh.u.tr.tile[dR][cg*8+1]=v0.y;
      sh.u.tr.tile[dR][cg*8+2]=v0.z; sh.u.tr.tile[dR][cg*8+3]=v0.w;
      sh.u.tr.tile[dR][cg*8+4]=v1.x; sh.u.tr.tile[dR][cg*8+5]=v1.y;
      sh.u.tr.tile[dR][cg*8+6]=v1.z; sh.u.tr.tile[dR][cg*8+7]=v1.w;
    }
    __syncthreads();
    {
      int nl = t >> 3, dg = t & 7;
      float4 w0, w1;
      w0.x = sh.u.tr.tile[dg*8+0][nl]; w0.y = sh.u.tr.tile[dg*8+1][nl];
      w0.z = sh.u.tr.tile[dg*8+2][nl]; w0.w = sh.u.tr.tile[dg*8+3][nl];
      w1.x = sh.u.tr.tile[dg*8+4][nl]; w1.y = sh.u.tr.tile[dg*8+5][nl];
      w1.z = sh.u.tr.tile[dg*8+6][nl]; w1.w = sh.u.tr.tile[dg*8+7][nl];
      float* dst = ws + WS_PTS_T + ((size_t)b*NPT + n0 + nl)*ND + dg*8;
      *reinterpret_cast<float4*>(dst)     = w0;
      *reinterpret_cast<float4*>(dst + 4) = w1;
    }
    __syncthreads();
  }
  for (int chunk = cbid; chunk < 128; chunk += NCONS) {
    int g = chunk*512 + t;
    int b = g >> 13, n = g & 8191;
    const float* xb = xyz + (size_t)b*3*NPT;
    float x = xb[n], y = xb[NPT+n], z = xb[2*NPT+n];
    float4 v; v.x=x; v.y=y; v.z=z; v.w=sq3(x,y,z);
    *reinterpret_cast<float4*>(ws + WS_XYZW + (size_t)g*4) = v;
  }
  __syncthreads();
  if (t == 0) {
    __hip_atomic_fetch_add(&syncp[0], 1, __ATOMIC_ACQ_REL, __HIP_MEMORY_SCOPE_AGENT);
    while (__hip_atomic_load(&syncp[0], __ATOMIC_RELAXED, __HIP_MEMORY_SCOPE_AGENT) < NCONS)
      __builtin_amdgcn_s_sleep(8);
    (void)__hip_atomic_load(&syncp[0], __ATOMIC_ACQUIRE, __HIP_MEMORY_SCOPE_AGENT);
  }
  __syncthreads();

  for (int g = t; g < 128*67; g += 512) {
    int o = g / 67, c = g - o*67;
    sh.u.c.W[o*69+c] = Wkern[g];
  }
  __syncthreads();

  for (int j = 0; j < NITER; j++) {
    const int i = cbid + j*NCONS;
    const bool active = (i < NB*NS);
    const int ii = active ? i : (NB*NS - 1);
    const int b = ii & 7, s = ii >> 3;

    if (t == 0) {
      int f;
      while ((f = __hip_atomic_load(&gfar[(size_t)b*NS + s], __ATOMIC_RELAXED, __HIP_MEMORY_SCOPE_AGENT)) == -1)
        __builtin_amdgcn_s_sleep(8);
      sh.u.c.farSlot = f;
    }
    __syncthreads();
    const int far = sh.u.c.farSlot;

    const float* xyzw = ws + WS_XYZW + (size_t)b*NPT*4;
    const float4 q = *reinterpret_cast<const float4*>(xyzw + (size_t)far*4);

    if (active) {
      if (t == 3) dout[OUT_FPS + (size_t)b*NS + s] = (float)far;
      else if (t < 3) dout[OUT_NEWXYZ + (size_t)b*3*NS + (size_t)t*NS + s] = (t==0) ? q.x : (t==1) ? q.y : q.z;
    }

#pragma unroll
    for (int i2 = 0; i2 < 16; i2++) {
      int n = t + (i2 << 9);
      float4 p = *reinterpret_cast<const float4*>(xyzw + (size_t)n*4);
      sh.u.c.u.dist[n] = knn_d(q.w, p.w, q.x, q.y, q.z, p.x, p.y, p.z);
    }
    __syncthreads();

    for (int r = 0; r < NK; r++) {
      float bv = __int_as_float(0x7F800000); int bi = NPT;
#pragma unroll
      for (int i2 = 0; i2 < 16; i2++) {
        int n = t + (i2 << 9);
        float v = sh.u.c.u.dist[n];
        if (v < bv) { bv = v; bi = n; }
      }
      unsigned uu = __float_as_uint(bv);
      uu ^= ((unsigned)((int)uu >> 31)) | 0x80000000u;
      unsigned long long key = ((unsigned long long)uu << 32) | (unsigned)bi;
#pragma unroll
      for (int m = 1; m < 64; m <<= 1) {
        unsigned long long o = __shfl_xor(key, m, 64);
        key = (o < key) ? o : key;
      }
      if ((t & 63) == 0) sh.u.c.kred[t >> 6] = key;
      __syncthreads();
      if (t == 0) {
        unsigned long long kmin = sh.u.c.kred[0];
#pragma unroll
        for (int w2 = 1; w2 < 8; w2++) { unsigned long long o = sh.u.c.kred[w2]; if (o < kmin) kmin = o; }
        int win = (int)(kmin & 0xFFFFFFFFull);
        sh.u.c.selIdx[r] = win;
        sh.u.c.u.dist[win] = __int_as_float(0x7F800000);
      }
      __syncthreads();
    }

    if (t < 256) {
      int k = t >> 4, cg = t & 15;
      int idx = sh.u.c.selIdx[k];
      float4 f = *reinterpret_cast<const float4*>(ws + WS_PTS_T + ((size_t)b*NPT + idx)*ND + cg*4);
      float* nprow = sh.u.c.u.p2.np + k*69;
      nprow[3+cg*4+0]=f.x; nprow[3+cg*4+1]=f.y; nprow[3+cg*4+2]=f.z; nprow[3+cg*4+3]=f.w;
      if (cg == 0) {
        float4 g4 = *reinterpret_cast<const float4*>(xyzw + (size_t)idx*4);
        nprow[0]=g4.x-q.x; nprow[1]=g4.y-q.y; nprow[2]=g4.z-q.z;
      }
    }
    __syncthreads();

    if (t < 256) {
      const int o = t & 127, khalf = t >> 7, k0 = khalf*8;
      float acc[8] = {0,0,0,0,0,0,0,0};
      const float* Wrow = sh.u.c.W + o*69;
      for (int c = 0; c < 67; c++) {
        float wv = Wrow[c];
#pragma unroll
        for (int kk = 0; kk < 8; kk++)
          acc[kk] = fmaf(wv, sh.u.c.u.p2.np[(k0+kk)*69 + c], acc[kk]);
      }
      float chp = 0.f;
#pragma unroll
      for (int kk = 0; kk < 8; kk++) {
        float a = acc[kk]; a = (a >= 0.f) ? a : 0.1f*a;
        sh.u.c.u.p2.ft[(k0+kk)*132 + o] = a; chp += a;
      }
      sh.u.c.u.p2.chred[khalf*128 + o] = chp;
    }
    __syncthreads();

    if (t < 128) sh.u.c.agg[t] = (sh.u.c.u.p2.chred[t] + sh.u.c.u.p2.chred[128+t]) * 0.0625f;
    if (t < 256) {
      int k = t & 15, og = t >> 4;
      float pp = 0.f;
#pragma unroll
      for (int jj = 0; jj < 8; jj++) pp += sh.u.c.u.p2.ft[k*132 + og*8 + jj];
      sh.u.c.u.p2.ptred[k*17 + og] = pp;
    }
    __syncthreads();
    if (t < 16) {
      float pv = 0.f;
#pragma unroll
      for (int og = 0; og < 16; og++) pv += sh.u.c.u.p2.ptred[t*17 + og];
      sh.u.c.agg[128 + t] = pv * 0.0078125f;
    }
    __syncthreads();

    if (t < 144) {
      float a = 0.f;
      const float* wr = Wlin + t*144;
      for (int c = 0; c < 144; c++) a = fmaf(wr[c], sh.u.c.agg[c], a);
      sh.u.c.a2[t] = (a >= 0.f) ? a : 0.1f*a;
    }
    __syncthreads();

    if (t < 128) {
      float a = 0.f;
      const float* wr = Wch + t*128;
      for (int c = 0; c < 128; c++) a = fmaf(wr[c], sh.u.c.a2[c], a);
      sh.u.c.gates[t] = 1.f / (1.f + expf(-a));
    } else if (t < 144) {
      int o = t - 128;
      float a = 0.f;
      const float* wr = Wpt + o*16;
      for (int c = 0; c < 16; c++) a = fmaf(wr[c], sh.u.c.a2[128+c], a);
      sh.u.c.gates[t] = 1.f / (1.f + expf(-a));
    }
    __syncthreads();

    if (t < 128 && active) {
      float sum = 0.f;
#pragma unroll
      for (int k = 0; k < 16; k++)
        sum = fmaf(sh.u.c.u.p2.ft[k*132 + t], sh.u.c.gates[128 + k], sum);
      dout[OUT_FEAT + ((size_t)b*NO + t)*NS + s] = sum * sh.u.c.gates[t] * 0.0625f;
    }
    __syncthreads();
  }
}

extern "C" void kernel_launch(void* const* d_in, const int* in_sizes, int n_in,
                              void* d_out, int out_size, void* d_ws, size_t ws_size,
                              hipStream_t stream) {
  (void)in_sizes; (void)n_in; (void)out_size; (void)ws_size;
  const float* xyz    = (const float*)d_in[0];
  const float* points = (const float*)d_in[1];
  const float* Wk     = (const float*)d_in[2];
  const float* Wl     = (const float*)d_in[3];
  const float* Wp     = (const float*)d_in[4];
  const float* Wc     = (const float*)d_in[5];
  float* ws  = (float*)d_ws;
  float* out = (float*)d_out;

  hipLaunchKernelGGL(k_init, dim3(32), dim3(512), 0, stream, ws);

  void* args[] = { (void*)&xyz, (void*)&points, (void*)&Wk, (void*)&Wl,
                   (void*)&Wp, (void*)&Wc, (void*)&ws, (void*)&out };
  hipLaunchCooperativeKernel(reinterpret_cast<void*>(k_mega),
                             dim3(NB + NCONS), dim3(512), args, 0, stream);
}

// Round 11
// 1991.965 us; speedup vs baseline: 1.0816x; 1.0816x over previous
//
#include <hip/hip_runtime.h>
#include <stdint.h>

// Problem constants
#define NB 8
#define NPT 8192
#define ND 64
#define NO 128
#define NS 2048
#define NK 16
#define NCONS 248   // consumer blocks
#define NITER 67    // ceil(B*S / NCONS) = ceil(16384/248)

typedef float f32x2 __attribute__((ext_vector_type(2)));

// Workspace layout (in floats)
constexpr int WS_PTS_T  = 0;                         // [B][N][64] transposed points
constexpr int WS_XYZW   = WS_PTS_T + NB*NPT*ND;      // [B][N][4] x,y,z,|p|^2
constexpr int WS_GFAR   = WS_XYZW + NB*NPT*4;        // int [B][S] center indices, -1 = not ready
constexpr int WS_SYNC   = WS_GFAR + NB*NS;           // int[32]: prep_done at 0

// Output layout (floats): new_xyz [B][3][S], out [B][O][S], fps_idx [B][S]
constexpr int OUT_NEWXYZ = 0;
constexpr int OUT_FEAT   = NB*3*NS;
constexpr int OUT_FPS    = OUT_FEAT + NB*NO*NS;

__device__ __forceinline__ float sq3(float x, float y, float z) {
#pragma clang fp contract(off)
  return (x*x + y*y) + z*z;
}

// packed squared distance for 2 points: bit-identical op order ((dx*dx+dy*dy)+dz*dz)
__device__ __forceinline__ f32x2 fps_d2(f32x2 px, f32x2 py, f32x2 pz, f32x2 cx, f32x2 cy, f32x2 cz) {
#pragma clang fp contract(off)
  f32x2 dx = px - cx, dy = py - cy, dz = pz - cz;
  return (dx*dx + dy*dy) + dz*dz;
}

__device__ __forceinline__ float knn_d(float qn, float pn,
                                       float qx,float qy,float qz,
                                       float px,float py,float pz) {
#pragma clang fp contract(off)
  float dot = (qx*px + qy*py) + qz*pz;
  return (qn + pn) - 2.0f*dot;
}

#define DPP_STEP_F(x, ctrl, rm, bm, op) { \
  int _v = __builtin_amdgcn_update_dpp(__float_as_int(x), __float_as_int(x), ctrl, rm, bm, false); \
  x = op(x, __int_as_float(_v)); }

__device__ __forceinline__ float wave_max_dpp(float x) {
  DPP_STEP_F(x, 0x111, 0xF, 0xF, fmaxf)  // row_shr:1
  DPP_STEP_F(x, 0x112, 0xF, 0xF, fmaxf)  // row_shr:2
  DPP_STEP_F(x, 0x114, 0xF, 0xF, fmaxf)  // row_shr:4
  DPP_STEP_F(x, 0x118, 0xF, 0xF, fmaxf)  // row_shr:8
  DPP_STEP_F(x, 0x142, 0xA, 0xF, fmaxf)  // row_bcast:15
  DPP_STEP_F(x, 0x143, 0xC, 0xF, fmaxf)  // row_bcast:31
  return x;                              // valid in lane 63
}
__device__ __forceinline__ float dpp8_max(float x) {
  DPP_STEP_F(x, 0x111, 0xF, 0xF, fmaxf)
  DPP_STEP_F(x, 0x112, 0xF, 0xF, fmaxf)
  DPP_STEP_F(x, 0x114, 0xF, 0xF, fmaxf)
  return x;                              // lane 7 = max of lanes 0..7
}

__global__ void k_init(float* __restrict__ ws) {
  int idx = blockIdx.x*512 + threadIdx.x;
  if (idx < NB*NS) ((int*)(ws + WS_GFAR))[idx] = -1;
  if (idx < 32)    ((int*)(ws + WS_SYNC))[idx] = 0;
}

struct MegaShared {
  union {
    struct {                                  // FPS producer (~128.3 KB)
      float lxyz[NPT][4];                     // x,y,z,pad -> 1 ds_read_b128 center broadcast
      unsigned long long wred[2][8];          // per-wave partials, parity-buffered
      int tag[2][8];                          // handshake tags (monotonic per parity slot)
    } f;
    struct { float tile[64][65]; } tr;        // prep transpose
    struct {                                  // consumer (~70 KB)
      float W[128*69];
      union {
        float dist[NPT];
        struct { float np[16*69]; float ft[16*132]; float chred[256]; float ptred[16*17]; } p2;
      } u;
      unsigned long long kred[8];
      int selIdx[16];
      float agg[144];
      float a2[144];
      float gates[144];
      int farSlot;
    } c;
  } u;
};

__global__ __launch_bounds__(512) void k_mega(const float* __restrict__ xyz,
                                              const float* __restrict__ points,
                                              const float* __restrict__ Wkern,
                                              const float* __restrict__ Wlin,
                                              const float* __restrict__ Wpt,
                                              const float* __restrict__ Wch,
                                              float* __restrict__ ws,
                                              float* __restrict__ dout) {
  __shared__ MegaShared sh;
  const int bid = blockIdx.x, t = threadIdx.x;
  int* syncp = (int*)(ws + WS_SYNC);
  int* gfar  = (int*)(ws + WS_GFAR);

  if (bid < NB) {
    // ================= FPS producer (barrier-free steady-state loop) =============
    const float* xb = xyz + (size_t)bid*3*NPT;
    f32x2 px2[8], py2[8], pz2[8], dist2[8];
    const int base = t << 4;
    const int w = t >> 6;
#pragma unroll
    for (int jj = 0; jj < 4; jj++) {
      float4 vx = *reinterpret_cast<const float4*>(xb + base + jj*4);
      float4 vy = *reinterpret_cast<const float4*>(xb + NPT + base + jj*4);
      float4 vz = *reinterpret_cast<const float4*>(xb + 2*NPT + base + jj*4);
      px2[jj*2+0] = f32x2{vx.x, vx.y}; px2[jj*2+1] = f32x2{vx.z, vx.w};
      py2[jj*2+0] = f32x2{vy.x, vy.y}; py2[jj*2+1] = f32x2{vy.z, vy.w};
      pz2[jj*2+0] = f32x2{vz.x, vz.y}; pz2[jj*2+1] = f32x2{vz.z, vz.w};
      dist2[jj*2+0] = f32x2{1e10f, 1e10f}; dist2[jj*2+1] = f32x2{1e10f, 1e10f};
      float xs[4] = {vx.x, vx.y, vx.z, vx.w};
      float ys[4] = {vy.x, vy.y, vy.z, vy.w};
      float zs[4] = {vz.x, vz.y, vz.z, vz.w};
#pragma unroll
      for (int i = 0; i < 4; i++) {
        float4 rec; rec.x = xs[i]; rec.y = ys[i]; rec.z = zs[i]; rec.w = 0.f;
        *reinterpret_cast<float4*>(&sh.u.f.lxyz[base + jj*4 + i][0]) = rec;
      }
    }
    if (t < 16) sh.u.f.tag[t >> 3][t & 7] = 0;
    __syncthreads();   // one-time: coords + tags staged

    int far = 0;
    int* gfb = gfar + (size_t)bid*NS;

    for (int s = 0; s < NS; s++) {
      // publish center s (fire-and-forget relaxed agent atomic; never drained — no barriers left)
      if (t == 0)
        __hip_atomic_store(&gfb[s], far, __ATOMIC_RELAXED, __HIP_MEMORY_SCOPE_AGENT);

      const float4 c4 = *reinterpret_cast<const float4*>(&sh.u.f.lxyz[far][0]);
      const f32x2 c2x = {c4.x, c4.x}, c2y = {c4.y, c4.y}, c2z = {c4.z, c4.z};

      // pass 1: packed dist + min update + running max (no index tracking)
      f32x2 vmax2 = {-1.0f, -1.0f};
#pragma unroll
      for (int j = 0; j < 8; j++) {
        f32x2 dd = fps_d2(px2[j], py2[j], pz2[j], c2x, c2y, c2z);
        f32x2 nd;
        nd.x = fminf(dist2[j].x, dd.x);
        nd.y = fminf(dist2[j].y, dd.y);
        dist2[j] = nd;
        vmax2.x = fmaxf(vmax2.x, nd.x);
        vmax2.y = fmaxf(vmax2.y, nd.y);
      }
      float bv = fmaxf(vmax2.x, vmax2.y);
      // pass 2: recover first (lowest) index equal to bv — descending overwrite
      int bi = base;
#pragma unroll
      for (int j = 7; j >= 0; --j) {
        if (dist2[j].y == bv) bi = base + 2*j + 1;
        if (dist2[j].x == bv) bi = base + 2*j;
      }
      // wave max via DPP, winner = lowest lane holding it (lowest index)
      float wm = wave_max_dpp(bv);
      float wmax = __int_as_float(__builtin_amdgcn_readlane(__float_as_int(wm), 63));
      unsigned long long eq = __ballot(bv == wmax);
      int winner = __ffsll((unsigned long long)eq) - 1;
      int wbi = __builtin_amdgcn_readlane(bi, winner);

      const int par = s & 1;
      const int mytag = (s >> 1) + 1;
      if ((t & 63) == 0) {
        sh.u.f.wred[par][w] = ((unsigned long long)__float_as_uint(wmax) << 32) | (unsigned)wbi;
        // release: orders the wred write before the tag becomes visible
        __hip_atomic_store(&sh.u.f.tag[par][w], mytag, __ATOMIC_RELEASE, __HIP_MEMORY_SCOPE_WORKGROUP);
      }
      // per-slot spin: lane waits only for its slot (t&7); wave exits when all 8 ready
      {
        int* tp = &sh.u.f.tag[par][t & 7];
        while (__hip_atomic_load(tp, __ATOMIC_ACQUIRE, __HIP_MEMORY_SCOPE_WORKGROUP) != mytag) {}
      }
      // stage 2: dpp8 max over the 8 slots; lowest-wave tie-break
      {
        unsigned long long kk = sh.u.f.wred[par][t & 7];
        float sv = __int_as_float((int)(unsigned)(kk >> 32));
        float sm = dpp8_max(sv);
        float M = __int_as_float(__builtin_amdgcn_readlane(__float_as_int(sm), 7));
        unsigned long long eqm = __ballot(sv == M) & 0xFFull;
        int wwin = __ffsll(eqm) - 1;
        far = __builtin_amdgcn_readlane((int)(kk & 0xFFFFFFFFull), wwin);
      }
    }
    return;
  }

  // ================= Consumer block (unchanged) =================
  const int cbid = bid - NB;   // 0..247

  for (int tile = cbid; tile < 1024; tile += NCONS) {
    const int b  = tile >> 7;
    const int n0 = (tile & 127) << 6;
    const float* pb = points + (size_t)b*ND*NPT;
    {
      int dR = t >> 3, cg = t & 7;
      const float* src = pb + (size_t)dR*NPT + n0 + cg*8;
      float4 v0 = *reinterpret_cast<const float4*>(src);
      float4 v1 = *reinterpret_cast<const float4*>(src + 4);
      sh.u.tr.tile[dR][cg*8+0]=v0.x; sh.u.tr.tile[dR][cg*8+1]=v0.y;
      sh.u.tr.tile[dR][cg*8+2]=v0.z; sh.u.tr.tile[dR][cg*8+3]=v0.w;
      sh.u.tr.tile[dR][cg*8+4]=v1.x; sh.u.tr.tile[dR][cg*8+5]=v1.y;
      sh.u.tr.tile[dR][cg*8+6]=v1.z; sh.u.tr.tile[dR][cg*8+7]=v1.w;
    }
    __syncthreads();
    {
      int nl = t >> 3, dg = t & 7;
      float4 w0, w1;
      w0.x = sh.u.tr.tile[dg*8+0][nl]; w0.y = sh.u.tr.tile[dg*8+1][nl];
      w0.z = sh.u.tr.tile[dg*8+2][nl]; w0.w = sh.u.tr.tile[dg*8+3][nl];
      w1.x = sh.u.tr.tile[dg*8+4][nl]; w1.y = sh.u.tr.tile[dg*8+5][nl];
      w1.z = sh.u.tr.tile[dg*8+6][nl]; w1.w = sh.u.tr.tile[dg*8+7][nl];
      float* dst = ws + WS_PTS_T + ((size_t)b*NPT + n0 + nl)*ND + dg*8;
      *reinterpret_cast<float4*>(dst)     = w0;
      *reinterpret_cast<float4*>(dst + 4) = w1;
    }
    __syncthreads();
  }
  for (int chunk = cbid; chunk < 128; chunk += NCONS) {
    int g = chunk*512 + t;
    int b = g >> 13, n = g & 8191;
    const float* xb = xyz + (size_t)b*3*NPT;
    float x = xb[n], y = xb[NPT+n], z = xb[2*NPT+n];
    float4 v; v.x=x; v.y=y; v.z=z; v.w=sq3(x,y,z);
    *reinterpret_cast<float4*>(ws + WS_XYZW + (size_t)g*4) = v;
  }
  __syncthreads();
  if (t == 0) {
    __hip_atomic_fetch_add(&syncp[0], 1, __ATOMIC_ACQ_REL, __HIP_MEMORY_SCOPE_AGENT);
    while (__hip_atomic_load(&syncp[0], __ATOMIC_RELAXED, __HIP_MEMORY_SCOPE_AGENT) < NCONS)
      __builtin_amdgcn_s_sleep(8);
    (void)__hip_atomic_load(&syncp[0], __ATOMIC_ACQUIRE, __HIP_MEMORY_SCOPE_AGENT);
  }
  __syncthreads();

  for (int g = t; g < 128*67; g += 512) {
    int o = g / 67, c = g - o*67;
    sh.u.c.W[o*69+c] = Wkern[g];
  }
  __syncthreads();

  for (int j = 0; j < NITER; j++) {
    const int i = cbid + j*NCONS;
    const bool active = (i < NB*NS);
    const int ii = active ? i : (NB*NS - 1);
    const int b = ii & 7, s = ii >> 3;

    if (t == 0) {
      int f;
      while ((f = __hip_atomic_load(&gfar[(size_t)b*NS + s], __ATOMIC_RELAXED, __HIP_MEMORY_SCOPE_AGENT)) == -1)
        __builtin_amdgcn_s_sleep(8);
      sh.u.c.farSlot = f;
    }
    __syncthreads();
    const int far = sh.u.c.farSlot;

    const float* xyzw = ws + WS_XYZW + (size_t)b*NPT*4;
    const float4 q = *reinterpret_cast<const float4*>(xyzw + (size_t)far*4);

    if (active) {
      if (t == 3) dout[OUT_FPS + (size_t)b*NS + s] = (float)far;
      else if (t < 3) dout[OUT_NEWXYZ + (size_t)b*3*NS + (size_t)t*NS + s] = (t==0) ? q.x : (t==1) ? q.y : q.z;
    }

#pragma unroll
    for (int i2 = 0; i2 < 16; i2++) {
      int n = t + (i2 << 9);
      float4 p = *reinterpret_cast<const float4*>(xyzw + (size_t)n*4);
      sh.u.c.u.dist[n] = knn_d(q.w, p.w, q.x, q.y, q.z, p.x, p.y, p.z);
    }
    __syncthreads();

    for (int r = 0; r < NK; r++) {
      float bv = __int_as_float(0x7F800000); int bi = NPT;
#pragma unroll
      for (int i2 = 0; i2 < 16; i2++) {
        int n = t + (i2 << 9);
        float v = sh.u.c.u.dist[n];
        if (v < bv) { bv = v; bi = n; }
      }
      unsigned uu = __float_as_uint(bv);
      uu ^= ((unsigned)((int)uu >> 31)) | 0x80000000u;
      unsigned long long key = ((unsigned long long)uu << 32) | (unsigned)bi;
#pragma unroll
      for (int m = 1; m < 64; m <<= 1) {
        unsigned long long o = __shfl_xor(key, m, 64);
        key = (o < key) ? o : key;
      }
      if ((t & 63) == 0) sh.u.c.kred[t >> 6] = key;
      __syncthreads();
      if (t == 0) {
        unsigned long long kmin = sh.u.c.kred[0];
#pragma unroll
        for (int w2 = 1; w2 < 8; w2++) { unsigned long long o = sh.u.c.kred[w2]; if (o < kmin) kmin = o; }
        int win = (int)(kmin & 0xFFFFFFFFull);
        sh.u.c.selIdx[r] = win;
        sh.u.c.u.dist[win] = __int_as_float(0x7F800000);
      }
      __syncthreads();
    }

    if (t < 256) {
      int k = t >> 4, cg = t & 15;
      int idx = sh.u.c.selIdx[k];
      float4 f = *reinterpret_cast<const float4*>(ws + WS_PTS_T + ((size_t)b*NPT + idx)*ND + cg*4);
      float* nprow = sh.u.c.u.p2.np + k*69;
      nprow[3+cg*4+0]=f.x; nprow[3+cg*4+1]=f.y; nprow[3+cg*4+2]=f.z; nprow[3+cg*4+3]=f.w;
      if (cg == 0) {
        float4 g4 = *reinterpret_cast<const float4*>(xyzw + (size_t)idx*4);
        nprow[0]=g4.x-q.x; nprow[1]=g4.y-q.y; nprow[2]=g4.z-q.z;
      }
    }
    __syncthreads();

    if (t < 256) {
      const int o = t & 127, khalf = t >> 7, k0 = khalf*8;
      float acc[8] = {0,0,0,0,0,0,0,0};
      const float* Wrow = sh.u.c.W + o*69;
      for (int c = 0; c < 67; c++) {
        float wv = Wrow[c];
#pragma unroll
        for (int kk = 0; kk < 8; kk++)
          acc[kk] = fmaf(wv, sh.u.c.u.p2.np[(k0+kk)*69 + c], acc[kk]);
      }
      float chp = 0.f;
#pragma unroll
      for (int kk = 0; kk < 8; kk++) {
        float a = acc[kk]; a = (a >= 0.f) ? a : 0.1f*a;
        sh.u.c.u.p2.ft[(k0+kk)*132 + o] = a; chp += a;
      }
      sh.u.c.u.p2.chred[khalf*128 + o] = chp;
    }
    __syncthreads();

    if (t < 128) sh.u.c.agg[t] = (sh.u.c.u.p2.chred[t] + sh.u.c.u.p2.chred[128+t]) * 0.0625f;
    if (t < 256) {
      int k = t & 15, og = t >> 4;
      float pp = 0.f;
#pragma unroll
      for (int jj = 0; jj < 8; jj++) pp += sh.u.c.u.p2.ft[k*132 + og*8 + jj];
      sh.u.c.u.p2.ptred[k*17 + og] = pp;
    }
    __syncthreads();
    if (t < 16) {
      float pv = 0.f;
#pragma unroll
      for (int og = 0; og < 16; og++) pv += sh.u.c.u.p2.ptred[t*17 + og];
      sh.u.c.agg[128 + t] = pv * 0.0078125f;
    }
    __syncthreads();

    if (t < 144) {
      float a = 0.f;
      const float* wr = Wlin + t*144;
      for (int c = 0; c < 144; c++) a = fmaf(wr[c], sh.u.c.agg[c], a);
      sh.u.c.a2[t] = (a >= 0.f) ? a : 0.1f*a;
    }
    __syncthreads();

    if (t < 128) {
      float a = 0.f;
      const float* wr = Wch + t*128;
      for (int c = 0; c < 128; c++) a = fmaf(wr[c], sh.u.c.a2[c], a);
      sh.u.c.gates[t] = 1.f / (1.f + expf(-a));
    } else if (t < 144) {
      int o = t - 128;
      float a = 0.f;
      const float* wr = Wpt + o*16;
      for (int c = 0; c < 16; c++) a = fmaf(wr[c], sh.u.c.a2[128+c], a);
      sh.u.c.gates[t] = 1.f / (1.f + expf(-a));
    }
    __syncthreads();

    if (t < 128 && active) {
      float sum = 0.f;
#pragma unroll
      for (int k = 0; k < 16; k++)
        sum = fmaf(sh.u.c.u.p2.ft[k*132 + t], sh.u.c.gates[128 + k], sum);
      dout[OUT_FEAT + ((size_t)b*NO + t)*NS + s] = sum * sh.u.c.gates[t] * 0.0625f;
    }
    __syncthreads();
  }
}

extern "C" void kernel_launch(void* const* d_in, const int* in_sizes, int n_in,
                              void* d_out, int out_size, void* d_ws, size_t ws_size,
                              hipStream_t stream) {
  (void)in_sizes; (void)n_in; (void)out_size; (void)ws_size;
  const float* xyz    = (const float*)d_in[0];
  const float* points = (const float*)d_in[1];
  const float* Wk     = (const float*)d_in[2];
  const float* Wl     = (const float*)d_in[3];
  const float* Wp     = (const float*)d_in[4];
  const float* Wc     = (const float*)d_in[5];
  float* ws  = (float*)d_ws;
  float* out = (float*)d_out;

  hipLaunchKernelGGL(k_init, dim3(32), dim3(512), 0, stream, ws);

  void* args[] = { (void*)&xyz, (void*)&points, (void*)&Wk, (void*)&Wl,
                   (void*)&Wp, (void*)&Wc, (void*)&ws, (void*)&out };
  hipLaunchCooperativeKernel(reinterpret_cast<void*>(k_mega),
                             dim3(NB + NCONS), dim3(512), args, 0, stream);
}

// Round 12
// 1865.941 us; speedup vs baseline: 1.1547x; 1.0675x over previous
//
#include <hip/hip_runtime.h>
#include <stdint.h>

// Problem constants
#define NB 8
#define NPT 8192
#define ND 64
#define NO 128
#define NS 2048
#define NK 16
#define NCONS 248   // consumer blocks
#define NITER 67    // ceil(B*S / NCONS) = ceil(16384/248)

typedef float f32x2 __attribute__((ext_vector_type(2)));

// Workspace layout (in floats)
constexpr int WS_PTS_T  = 0;                         // [B][N][64] transposed points
constexpr int WS_XYZW   = WS_PTS_T + NB*NPT*ND;      // [B][N][4] x,y,z,|p|^2
constexpr int WS_GFAR   = WS_XYZW + NB*NPT*4;        // int [B][S] center indices, -1 = not ready
constexpr int WS_SYNC   = WS_GFAR + NB*NS;           // int[32]: prep_done at 0

// Output layout (floats): new_xyz [B][3][S], out [B][O][S], fps_idx [B][S]
constexpr int OUT_NEWXYZ = 0;
constexpr int OUT_FEAT   = NB*3*NS;
constexpr int OUT_FPS    = OUT_FEAT + NB*NO*NS;

__device__ __forceinline__ float sq3(float x, float y, float z) {
#pragma clang fp contract(off)
  return (x*x + y*y) + z*z;
}

// packed squared distance for 2 points: bit-identical op order ((dx*dx+dy*dy)+dz*dz)
__device__ __forceinline__ f32x2 fps_d2(f32x2 px, f32x2 py, f32x2 pz, f32x2 cx, f32x2 cy, f32x2 cz) {
#pragma clang fp contract(off)
  f32x2 dx = px - cx, dy = py - cy, dz = pz - cz;
  return (dx*dx + dy*dy) + dz*dz;
}

__device__ __forceinline__ float knn_d(float qn, float pn,
                                       float qx,float qy,float qz,
                                       float px,float py,float pz) {
#pragma clang fp contract(off)
  float dot = (qx*px + qy*py) + qz*pz;
  return (qn + pn) - 2.0f*dot;
}

#define DPP_STEP_F(x, ctrl, rm, bm, op) { \
  int _v = __builtin_amdgcn_update_dpp(__float_as_int(x), __float_as_int(x), ctrl, rm, bm, false); \
  x = op(x, __int_as_float(_v)); }
#define DPP_STEP_U(x, ctrl, rm, cmp) { \
  unsigned _v = (unsigned)__builtin_amdgcn_update_dpp((int)x, (int)x, ctrl, rm, 0xF, false); \
  x = (_v cmp x) ? _v : x; }

__device__ __forceinline__ float wave_max_dpp(float x) {
  DPP_STEP_F(x, 0x111, 0xF, 0xF, fmaxf)  // row_shr:1
  DPP_STEP_F(x, 0x112, 0xF, 0xF, fmaxf)  // row_shr:2
  DPP_STEP_F(x, 0x114, 0xF, 0xF, fmaxf)  // row_shr:4
  DPP_STEP_F(x, 0x118, 0xF, 0xF, fmaxf)  // row_shr:8
  DPP_STEP_F(x, 0x142, 0xA, 0xF, fmaxf)  // row_bcast:15
  DPP_STEP_F(x, 0x143, 0xC, 0xF, fmaxf)  // row_bcast:31
  return x;                              // valid in lane 63
}
__device__ __forceinline__ float wave_min_dpp(float x) {
  DPP_STEP_F(x, 0x111, 0xF, 0xF, fminf)
  DPP_STEP_F(x, 0x112, 0xF, 0xF, fminf)
  DPP_STEP_F(x, 0x114, 0xF, 0xF, fminf)
  DPP_STEP_F(x, 0x118, 0xF, 0xF, fminf)
  DPP_STEP_F(x, 0x142, 0xA, 0xF, fminf)
  DPP_STEP_F(x, 0x143, 0xC, 0xF, fminf)
  return x;
}
__device__ __forceinline__ unsigned wave_umin_dpp(unsigned x) {
  DPP_STEP_U(x, 0x111, 0xF, <) DPP_STEP_U(x, 0x112, 0xF, <) DPP_STEP_U(x, 0x114, 0xF, <)
  DPP_STEP_U(x, 0x118, 0xF, <) DPP_STEP_U(x, 0x142, 0xA, <) DPP_STEP_U(x, 0x143, 0xC, <)
  return x;
}
__device__ __forceinline__ float dpp8_max(float x) {
  DPP_STEP_F(x, 0x111, 0xF, 0xF, fmaxf)
  DPP_STEP_F(x, 0x112, 0xF, 0xF, fmaxf)
  DPP_STEP_F(x, 0x114, 0xF, 0xF, fmaxf)
  return x;                              // lane 7 = max of lanes 0..7
}

__global__ void k_init(float* __restrict__ ws) {
  int idx = blockIdx.x*512 + threadIdx.x;
  if (idx < NB*NS) ((int*)(ws + WS_GFAR))[idx] = -1;
  if (idx < 32)    ((int*)(ws + WS_SYNC))[idx] = 0;
}

struct MegaShared {
  union {
    struct {                                  // FPS producer (~128.2 KB)
      float lxyz[NPT][4];                     // x,y,z,pad -> 1 ds_read_b128 center broadcast
      unsigned long long wred[2][8];
    } f;
    struct { float tile[64][65]; } tr;        // prep transpose
    struct {                                  // consumer (~70 KB)
      float W[128*69];
      union {
        float dist[NPT];
        struct { float np[16*69]; float ft[16*132]; float chred[256]; float ptred[16*17]; } p2;
      } u;
      unsigned long long kred[2][8];          // parity-buffered round partials
      float agg[144];
      float a2[144];
      float gates[144];
      int farSlot;
    } c;
  } u;
};

__global__ __launch_bounds__(512) void k_mega(const float* __restrict__ xyz,
                                              const float* __restrict__ points,
                                              const float* __restrict__ Wkern,
                                              const float* __restrict__ Wlin,
                                              const float* __restrict__ Wpt,
                                              const float* __restrict__ Wch,
                                              float* __restrict__ ws,
                                              float* __restrict__ dout) {
  __shared__ MegaShared sh;
  const int bid = blockIdx.x, t = threadIdx.x;
  int* syncp = (int*)(ws + WS_SYNC);
  int* gfar  = (int*)(ws + WS_GFAR);

  if (bid < NB) {
    // ================= FPS producer (R8 structure — best measured) =============
    const float* xb = xyz + (size_t)bid*3*NPT;
    f32x2 px2[8], py2[8], pz2[8], dist2[8];
    const int base = t << 4;
#pragma unroll
    for (int jj = 0; jj < 4; jj++) {
      float4 vx = *reinterpret_cast<const float4*>(xb + base + jj*4);
      float4 vy = *reinterpret_cast<const float4*>(xb + NPT + base + jj*4);
      float4 vz = *reinterpret_cast<const float4*>(xb + 2*NPT + base + jj*4);
      px2[jj*2+0] = f32x2{vx.x, vx.y}; px2[jj*2+1] = f32x2{vx.z, vx.w};
      py2[jj*2+0] = f32x2{vy.x, vy.y}; py2[jj*2+1] = f32x2{vy.z, vy.w};
      pz2[jj*2+0] = f32x2{vz.x, vz.y}; pz2[jj*2+1] = f32x2{vz.z, vz.w};
      dist2[jj*2+0] = f32x2{1e10f, 1e10f}; dist2[jj*2+1] = f32x2{1e10f, 1e10f};
      float xs[4] = {vx.x, vx.y, vx.z, vx.w};
      float ys[4] = {vy.x, vy.y, vy.z, vy.w};
      float zs[4] = {vz.x, vz.y, vz.z, vz.w};
#pragma unroll
      for (int i = 0; i < 4; i++) {
        float4 rec; rec.x = xs[i]; rec.y = ys[i]; rec.z = zs[i]; rec.w = 0.f;
        *reinterpret_cast<float4*>(&sh.u.f.lxyz[base + jj*4 + i][0]) = rec;
      }
    }
    __syncthreads();

    int far = 0;
    int* gfb = gfar + (size_t)bid*NS;

    for (int s = 0; s < NS; s++) {
      // publish center s (relaxed agent atomic — payload IS the handshake)
      if (t == 0)
        __hip_atomic_store(&gfb[s], far, __ATOMIC_RELAXED, __HIP_MEMORY_SCOPE_AGENT);

      const float4 c4 = *reinterpret_cast<const float4*>(&sh.u.f.lxyz[far][0]);
      const f32x2 c2x = {c4.x, c4.x}, c2y = {c4.y, c4.y}, c2z = {c4.z, c4.z};

      f32x2 vmax2 = {-1.0f, -1.0f};
#pragma unroll
      for (int j = 0; j < 8; j++) {
        f32x2 dd = fps_d2(px2[j], py2[j], pz2[j], c2x, c2y, c2z);
        f32x2 nd;
        nd.x = fminf(dist2[j].x, dd.x);
        nd.y = fminf(dist2[j].y, dd.y);
        dist2[j] = nd;
        vmax2.x = fmaxf(vmax2.x, nd.x);
        vmax2.y = fmaxf(vmax2.y, nd.y);
      }
      float bv = fmaxf(vmax2.x, vmax2.y);
      int bi = base;
#pragma unroll
      for (int j = 7; j >= 0; --j) {
        if (dist2[j].y == bv) bi = base + 2*j + 1;
        if (dist2[j].x == bv) bi = base + 2*j;
      }
      float wm = wave_max_dpp(bv);
      float wmax = __int_as_float(__builtin_amdgcn_readlane(__float_as_int(wm), 63));
      unsigned long long eq = __ballot(bv == wmax);
      int winner = __ffsll((unsigned long long)eq) - 1;
      int wbi = __builtin_amdgcn_readlane(bi, winner);
      const int par = s & 1;
      if ((t & 63) == 0)
        sh.u.f.wred[par][t >> 6] = ((unsigned long long)__float_as_uint(wmax) << 32) | (unsigned)wbi;
      __syncthreads();
      {
        unsigned long long kk = sh.u.f.wred[par][t & 7];
        float sv = __int_as_float((int)(unsigned)(kk >> 32));
        float sm = dpp8_max(sv);
        float M = __int_as_float(__builtin_amdgcn_readlane(__float_as_int(sm), 7));
        unsigned long long eqm = __ballot(sv == M) & 0xFFull;
        int wwin = __ffsll(eqm) - 1;
        far = __builtin_amdgcn_readlane((int)(kk & 0xFFFFFFFFull), wwin);
      }
    }
    return;
  }

  // ================= Consumer block =================
  const int cbid = bid - NB;   // 0..247

  for (int tile = cbid; tile < 1024; tile += NCONS) {
    const int b  = tile >> 7;
    const int n0 = (tile & 127) << 6;
    const float* pb = points + (size_t)b*ND*NPT;
    {
      int dR = t >> 3, cg = t & 7;
      const float* src = pb + (size_t)dR*NPT + n0 + cg*8;
      float4 v0 = *reinterpret_cast<const float4*>(src);
      float4 v1 = *reinterpret_cast<const float4*>(src + 4);
      sh.u.tr.tile[dR][cg*8+0]=v0.x; sh.u.tr.tile[dR][cg*8+1]=v0.y;
      sh.u.tr.tile[dR][cg*8+2]=v0.z; sh.u.tr.tile[dR][cg*8+3]=v0.w;
      sh.u.tr.tile[dR][cg*8+4]=v1.x; sh.u.tr.tile[dR][cg*8+5]=v1.y;
      sh.u.tr.tile[dR][cg*8+6]=v1.z; sh.u.tr.tile[dR][cg*8+7]=v1.w;
    }
    __syncthreads();
    {
      int nl = t >> 3, dg = t & 7;
      float4 w0, w1;
      w0.x = sh.u.tr.tile[dg*8+0][nl]; w0.y = sh.u.tr.tile[dg*8+1][nl];
      w0.z = sh.u.tr.tile[dg*8+2][nl]; w0.w = sh.u.tr.tile[dg*8+3][nl];
      w1.x = sh.u.tr.tile[dg*8+4][nl]; w1.y = sh.u.tr.tile[dg*8+5][nl];
      w1.z = sh.u.tr.tile[dg*8+6][nl]; w1.w = sh.u.tr.tile[dg*8+7][nl];
      float* dst = ws + WS_PTS_T + ((size_t)b*NPT + n0 + nl)*ND + dg*8;
      *reinterpret_cast<float4*>(dst)     = w0;
      *reinterpret_cast<float4*>(dst + 4) = w1;
    }
    __syncthreads();
  }
  for (int chunk = cbid; chunk < 128; chunk += NCONS) {
    int g = chunk*512 + t;
    int b = g >> 13, n = g & 8191;
    const float* xb = xyz + (size_t)b*3*NPT;
    float x = xb[n], y = xb[NPT+n], z = xb[2*NPT+n];
    float4 v; v.x=x; v.y=y; v.z=z; v.w=sq3(x,y,z);
    *reinterpret_cast<float4*>(ws + WS_XYZW + (size_t)g*4) = v;
  }
  __syncthreads();
  if (t == 0) {
    __hip_atomic_fetch_add(&syncp[0], 1, __ATOMIC_ACQ_REL, __HIP_MEMORY_SCOPE_AGENT);
    while (__hip_atomic_load(&syncp[0], __ATOMIC_RELAXED, __HIP_MEMORY_SCOPE_AGENT) < NCONS)
      __builtin_amdgcn_s_sleep(8);
    (void)__hip_atomic_load(&syncp[0], __ATOMIC_ACQUIRE, __HIP_MEMORY_SCOPE_AGENT);
  }
  __syncthreads();

  for (int g = t; g < 128*67; g += 512) {
    int o = g / 67, c = g - o*67;
    sh.u.c.W[o*69+c] = Wkern[g];
  }
  __syncthreads();

  const int myK = t >> 4;  // gather row this thread will own in phase C (t<256)

  for (int j = 0; j < NITER; j++) {
    const int i = cbid + j*NCONS;
    const bool active = (i < NB*NS);
    const int ii = active ? i : (NB*NS - 1);
    const int b = ii & 7, s = ii >> 3;

    if (t == 0) {
      int f;
      while ((f = __hip_atomic_load(&gfar[(size_t)b*NS + s], __ATOMIC_RELAXED, __HIP_MEMORY_SCOPE_AGENT)) == -1)
        __builtin_amdgcn_s_sleep(8);
      sh.u.c.farSlot = f;
    }
    __syncthreads();
    const int far = sh.u.c.farSlot;

    const float* xyzw = ws + WS_XYZW + (size_t)b*NPT*4;
    const float4 q = *reinterpret_cast<const float4*>(xyzw + (size_t)far*4);

    if (active) {
      if (t == 3) dout[OUT_FPS + (size_t)b*NS + s] = (float)far;
      else if (t < 3) dout[OUT_NEWXYZ + (size_t)b*3*NS + (size_t)t*NS + s] = (t==0) ? q.x : (t==1) ? q.y : q.z;
    }

    // phase A: distance row into LDS
#pragma unroll
    for (int i2 = 0; i2 < 16; i2++) {
      int n = t + (i2 << 9);
      float4 p = *reinterpret_cast<const float4*>(xyzw + (size_t)n*4);
      sh.u.c.u.dist[n] = knn_d(q.w, p.w, q.x, q.y, q.z, p.x, p.y, p.z);
    }
    __syncthreads();

    // phase B: stable top-16, ONE barrier/round, two-phase DPP reduce (exact)
    int exclWin = NPT;      // newest winner (its LDS mark may not be visible yet)
    int myIdx = 0;          // gather index captured when r == myK
    for (int r = 0; r < NK; r++) {
      float bv = __int_as_float(0x7F800000); int bi = NPT;
#pragma unroll
      for (int i2 = 0; i2 < 16; i2++) {
        int n = t + (i2 << 9);
        float v = sh.u.c.u.dist[n];
        if (n != exclWin && v < bv) { bv = v; bi = n; }
      }
      // two-phase wave reduce: min value, then min index among value-matching lanes
      float wmv = wave_min_dpp(bv);
      float M = __int_as_float(__builtin_amdgcn_readlane(__float_as_int(wmv), 63));
      unsigned cand = (bv == M) ? (unsigned)bi : 0xFFFFFFFFu;
      unsigned wcv = wave_umin_dpp(cand);
      unsigned widx = (unsigned)__builtin_amdgcn_readlane((int)wcv, 63);
      if ((t & 63) == 0)
        sh.u.c.kred[r & 1][t >> 6] = ((unsigned long long)__float_as_uint(M) << 32) | widx;
      __syncthreads();
      // redundant cross-wave pick (exact float compare + idx tie-break)
      unsigned long long k0 = sh.u.c.kred[r & 1][0];
      float best = __int_as_float((int)(unsigned)(k0 >> 32));
      unsigned bidx = (unsigned)(k0 & 0xFFFFFFFFull);
#pragma unroll
      for (int w2 = 1; w2 < 8; w2++) {
        unsigned long long kk = sh.u.c.kred[r & 1][w2];
        float v2 = __int_as_float((int)(unsigned)(kk >> 32));
        unsigned ix = (unsigned)(kk & 0xFFFFFFFFull);
        if (v2 < best || (v2 == best && ix < bidx)) { best = v2; bidx = ix; }
      }
      const int win = (int)bidx;
      if (r == myK) myIdx = win;
      // owner marks (skip last round: dist aliases np and nothing reads it after)
      if (r < NK-1 && (win & 511) == t) sh.u.c.u.dist[win] = __int_as_float(0x7F800000);
      exclWin = win;
    }
    // no barrier needed: all dist reads completed before round-15's barrier;
    // round-15 mark suppressed; np writes below race with nothing.

    // phase C: gather grouped features (t<256)
    if (t < 256) {
      int k = myK, cg = t & 15;
      int idx = myIdx;
      float4 f = *reinterpret_cast<const float4*>(ws + WS_PTS_T + ((size_t)b*NPT + idx)*ND + cg*4);
      float* nprow = sh.u.c.u.p2.np + k*69;
      nprow[3+cg*4+0]=f.x; nprow[3+cg*4+1]=f.y; nprow[3+cg*4+2]=f.z; nprow[3+cg*4+3]=f.w;
      if (cg == 0) {
        float4 g4 = *reinterpret_cast<const float4*>(xyzw + (size_t)idx*4);
        nprow[0]=g4.x-q.x; nprow[1]=g4.y-q.y; nprow[2]=g4.z-q.z;
      }
    }
    __syncthreads();

    // phase E: feat[o][k] = leaky(W . np)  (t<256)
    if (t < 256) {
      const int o = t & 127, khalf = t >> 7, k0h = khalf*8;
      float acc[8] = {0,0,0,0,0,0,0,0};
      const float* Wrow = sh.u.c.W + o*69;
      for (int c = 0; c < 67; c++) {
        float wv = Wrow[c];
#pragma unroll
        for (int kk = 0; kk < 8; kk++)
          acc[kk] = fmaf(wv, sh.u.c.u.p2.np[(k0h+kk)*69 + c], acc[kk]);
      }
      float chp = 0.f;
#pragma unroll
      for (int kk = 0; kk < 8; kk++) {
        float a = acc[kk]; a = (a >= 0.f) ? a : 0.1f*a;
        sh.u.c.u.p2.ft[(k0h+kk)*132 + o] = a; chp += a;
      }
      sh.u.c.u.p2.chred[khalf*128 + o] = chp;
    }
    __syncthreads();

    // phase F: ch_avg + pt_avg -> agg[144]
    if (t < 128) sh.u.c.agg[t] = (sh.u.c.u.p2.chred[t] + sh.u.c.u.p2.chred[128+t]) * 0.0625f;
    if (t < 256) {
      int k = t & 15, og = t >> 4;
      float pp = 0.f;
#pragma unroll
      for (int jj = 0; jj < 8; jj++) pp += sh.u.c.u.p2.ft[k*132 + og*8 + jj];
      sh.u.c.u.p2.ptred[k*17 + og] = pp;
    }
    __syncthreads();
    if (t < 16) {
      float pv = 0.f;
#pragma unroll
      for (int og = 0; og < 16; og++) pv += sh.u.c.u.p2.ptred[t*17 + og];
      sh.u.c.agg[128 + t] = pv * 0.0078125f;
    }
    __syncthreads();

    if (t < 144) {
      float a = 0.f;
      const float* wr = Wlin + t*144;
      for (int c = 0; c < 144; c++) a = fmaf(wr[c], sh.u.c.agg[c], a);
      sh.u.c.a2[t] = (a >= 0.f) ? a : 0.1f*a;
    }
    __syncthreads();

    if (t < 128) {
      float a = 0.f;
      const float* wr = Wch + t*128;
      for (int c = 0; c < 128; c++) a = fmaf(wr[c], sh.u.c.a2[c], a);
      sh.u.c.gates[t] = 1.f / (1.f + expf(-a));
    } else if (t < 144) {
      int o = t - 128;
      float a = 0.f;
      const float* wr = Wpt + o*16;
      for (int c = 0; c < 16; c++) a = fmaf(wr[c], sh.u.c.a2[128+c], a);
      sh.u.c.gates[t] = 1.f / (1.f + expf(-a));
    }
    __syncthreads();

    if (t < 128 && active) {
      float sum = 0.f;
#pragma unroll
      for (int k = 0; k < 16; k++)
        sum = fmaf(sh.u.c.u.p2.ft[k*132 + t], sh.u.c.gates[128 + k], sum);
      dout[OUT_FEAT + ((size_t)b*NO + t)*NS + s] = sum * sh.u.c.gates[t] * 0.0625f;
    }
    __syncthreads();
  }
}

extern "C" void kernel_launch(void* const* d_in, const int* in_sizes, int n_in,
                              void* d_out, int out_size, void* d_ws, size_t ws_size,
                              hipStream_t stream) {
  (void)in_sizes; (void)n_in; (void)out_size; (void)ws_size;
  const float* xyz    = (const float*)d_in[0];
  const float* points = (const float*)d_in[1];
  const float* Wk     = (const float*)d_in[2];
  const float* Wl     = (const float*)d_in[3];
  const float* Wp     = (const float*)d_in[4];
  const float* Wc     = (const float*)d_in[5];
  float* ws  = (float*)d_ws;
  float* out = (float*)d_out;

  hipLaunchKernelGGL(k_init, dim3(32), dim3(512), 0, stream, ws);

  void* args[] = { (void*)&xyz, (void*)&points, (void*)&Wk, (void*)&Wl,
                   (void*)&Wp, (void*)&Wc, (void*)&ws, (void*)&out };
  hipLaunchCooperativeKernel(reinterpret_cast<void*>(k_mega),
                             dim3(NB + NCONS), dim3(512), args, 0, stream);
}